// Round 2
// baseline (44860.294 us; speedup 1.0000x reference)
//
#include <hip/hip_runtime.h>
#include <hip/hip_bf16.h>

#define Bq   1024
#define NQS  15
#define NCS  18
#define NMSS 20
#define NPPc 36
#define NN   36864
#define NEg  138240
#define DD   128
#define NTD  16
#define NP   5
#define NT   3

#define NODE_CH 18432   // node-MLP row chunk (2 chunks)
#define EDGE_CH 17280   // edge-MLP row chunk (8 chunks)

#define AK_PLAIN   0
#define AK_CONCAT2 1
#define AK_EDGE    2
#define AK_NFENC   3
#define EP_RELU    0
#define EP_BIAS    1
#define EP_SCATTER 2

struct GemmParams {
  const float* A0; int lda0;
  const float* A1; int lda1;
  const float* W;
  const float* bias;
  float* C; int ldc;
  int K;
  int Nout;
  int row_base;
  const int* from_idx;
  const int* to_idx;
  const float* edge_feat;   // also node_features for AK_NFENC
  const float* W_ee;        // also W_ne for AK_NFENC
  const float* b_ee;        // also b_ne for AK_NFENC
  const float* mult;
  float* agg;
};

template<int AKIND>
__device__ __forceinline__ float loadA(const GemmParams& p, int row, int k) {
  if (AKIND == AK_PLAIN) {
    return p.A0[(long)row * p.lda0 + k];
  } else if (AKIND == AK_CONCAT2) {
    if (k < DD) return p.A0[(long)row * p.lda0 + k];
    return p.A1[(long)row * p.lda1 + (k - DD)];
  } else if (AKIND == AK_EDGE) {
    int e = p.row_base + row;
    if (k < DD)   return p.A0[(long)p.from_idx[e] * DD + k];
    if (k < 2*DD) return p.A0[(long)p.to_idx[e]   * DD + (k - DD)];
    int d = k - 2*DD;
    return p.edge_feat[e] * p.W_ee[d] + p.b_ee[d];
  } else {  // AK_NFENC: [nf_enc | zeros]
    if (k < DD) { int n = p.row_base + row; return p.edge_feat[n] * p.W_ee[k] + p.b_ee[k]; }
    return 0.f;
  }
}

// Tiled GEMM: C[M x Nout] = epi(A[M x K] @ W[K x Nout] + bias)
// BM=128, BN=64, BK=16, 256 threads, 8x4 outputs/thread.
template<int AKIND, int EPI>
__global__ __launch_bounds__(256)
void gemm_mlp(GemmParams p) {
  const int BM = 128, BN = 64, BK = 16;
  __shared__ float As[BK][BM + 1];
  __shared__ float Ws[BK][BN + 1];
  const int tid  = threadIdx.x;
  const int row0 = blockIdx.x * BM;
  const int col0 = blockIdx.y * BN;
  const int tm = tid & 15;   // rows tm*8 .. tm*8+7
  const int tn = tid >> 4;   // cols tn*4 .. tn*4+3

  float acc[8][4];
#pragma unroll
  for (int i = 0; i < 8; ++i)
#pragma unroll
    for (int j = 0; j < 4; ++j) acc[i][j] = 0.f;

  for (int k0 = 0; k0 < p.K; k0 += BK) {
    for (int i = tid; i < BM * BK; i += 256) {
      int r = i >> 4, k = i & 15;
      As[k][r] = loadA<AKIND>(p, row0 + r, k0 + k);
    }
    for (int i = tid; i < BK * BN; i += 256) {
      int k = i >> 6, c = i & 63;
      Ws[k][c] = p.W[(long)(k0 + k) * p.Nout + col0 + c];
    }
    __syncthreads();
#pragma unroll
    for (int kk = 0; kk < BK; ++kk) {
      float a[8], b[4];
#pragma unroll
      for (int i = 0; i < 8; ++i) a[i] = As[kk][tm * 8 + i];
#pragma unroll
      for (int j = 0; j < 4; ++j) b[j] = Ws[kk][tn * 4 + j];
#pragma unroll
      for (int i = 0; i < 8; ++i)
#pragma unroll
        for (int j = 0; j < 4; ++j) acc[i][j] += a[i] * b[j];
    }
    __syncthreads();
  }

#pragma unroll
  for (int i = 0; i < 8; ++i) {
    int row = row0 + tm * 8 + i;
#pragma unroll
    for (int j = 0; j < 4; ++j) {
      int col = col0 + tn * 4 + j;
      float v = acc[i][j] + p.bias[col];
      if (EPI == EP_RELU) {
        p.C[(long)row * p.ldc + col] = v > 0.f ? v : 0.f;
      } else if (EPI == EP_BIAS) {
        p.C[(long)row * p.ldc + col] = v;
      } else {  // EP_SCATTER
        int e = p.row_base + row;
        float mf = p.mult[e];
        if (mf != 0.f) atomicAdd(&p.agg[(long)p.to_idx[e] * DD + col], v * mf);
      }
    }
  }
}

// Per batch: mq (20x16, rows>=15 zero), mc (20x16, rows>=18 zero) from block5 of blk.
__global__ __launch_bounds__(256)
void mqmc_kernel(const float* blk, const float* W_t1, const float* b_t1,
                 const float* W_t2, const float* b_t2, float* mq, float* mc) {
  int b = blockIdx.x, tid = threadIdx.x;
  __shared__ float xs[33][DD];
  __shared__ float h1[33][NTD];
  for (int i = tid; i < NMSS * NTD; i += 256) {
    int r = i / NTD;
    if (r >= NQS) mq[(long)b * NMSS * NTD + i] = 0.f;
    if (r >= NCS) mc[(long)b * NMSS * NTD + i] = 0.f;
  }
  for (int i = tid; i < 33 * DD; i += 256) {
    int r = i >> 7, d = i & 127;
    int node = (r < NQS) ? b * NPPc + r : b * NPPc + NCS + (r - NQS);
    xs[r][d] = blk[(long)node * 640 + 512 + d];
  }
  __syncthreads();
  for (int i = tid; i < 33 * NTD; i += 256) {
    int r = i / NTD, c = i % NTD;
    float s = b_t1[c];
    for (int k = 0; k < DD; ++k) s += xs[r][k] * W_t1[k * NTD + c];
    h1[r][c] = s > 0.f ? s : 0.f;
  }
  __syncthreads();
  for (int i = tid; i < 33 * NTD; i += 256) {
    int r = i / NTD, c = i % NTD;
    float s = b_t2[c];
    for (int k = 0; k < NTD; ++k) s += h1[r][k] * W_t2[k * NTD + c];
    if (r < NQS) mq[(long)b * NMSS * NTD + r * NTD + c] = s;
    else         mc[(long)b * NMSS * NTD + (r - NQS) * NTD + c] = s;
  }
}

__global__ __launch_bounds__(64)
void sinkhorn_kernel(const float* mq, const float* mc, float* plan) {
  int b = blockIdx.x, tid = threadIdx.x;
  __shared__ float la[NMSS][NMSS];
  __shared__ float lq[NMSS][NTD], lc[NMSS][NTD];
  for (int i = tid; i < NMSS * NTD; i += 64) {
    lq[i / NTD][i % NTD] = mq[(long)b * 320 + i];
    lc[i / NTD][i % NTD] = mc[(long)b * 320 + i];
  }
  __syncthreads();
  for (int i = tid; i < 400; i += 64) {
    int q = i / 20, c = i % 20;
    float s = 0.f;
    for (int t = 0; t < NTD; ++t) s += lq[q][t] * lc[c][t];
    la[q][c] = s * 10.f;  // / SINKHORN_TEMP
  }
  __syncthreads();
  for (int it = 0; it < 10; ++it) {
    if (tid < 20) {
      float m = -1e30f;
      for (int c = 0; c < 20; ++c) m = fmaxf(m, la[tid][c]);
      float s = 0.f;
      for (int c = 0; c < 20; ++c) s += expf(la[tid][c] - m);
      float l = m + logf(s);
      for (int c = 0; c < 20; ++c) la[tid][c] -= l;
    }
    __syncthreads();
    if (tid < 20) {
      float m = -1e30f;
      for (int q = 0; q < 20; ++q) m = fmaxf(m, la[q][tid]);
      float s = 0.f;
      for (int q = 0; q < 20; ++q) s += expf(la[q][tid] - m);
      float l = m + logf(s);
      for (int q = 0; q < 20; ++q) la[q][tid] -= l;
    }
    __syncthreads();
  }
  for (int i = tid; i < 400; i += 64) plan[(long)b * 400 + i] = expf(la[i / 20][i % 20]);
}

// mixb (512-wide: mixed blocks 1..4) from blk (640-wide fresh blocks 1..5)
__global__ __launch_bounds__(256)
void mix_kernel(const float* blk, const float* plan, float* mix) {
  int b = blockIdx.x, tid = threadIdx.x;
  __shared__ float pl[400];
  for (int i = tid; i < 400; i += 256) pl[i] = plan[(long)b * 400 + i];
  __syncthreads();
  const float* base = blk + (long)b * NPPc * 640;
  float* obase      = mix + (long)b * NPPc * 512;
  for (int f = tid; f < 512; f += 256) {
    float oq[18], oc[18];
    for (int j = 0; j < 18; ++j) {
      oq[j] = base[(long)j * 640 + f];
      oc[j] = base[(long)(18 + j) * 640 + f];
    }
    for (int j = 0; j < 18; ++j) {
      float aq = 0.f, ac = 0.f;
      for (int k = 0; k < 18; ++k) {
        aq += pl[j * 20 + k] * oc[k];
        ac += pl[k * 20 + j] * oq[k];
      }
      obase[(long)j * 512 + f]        = aq;
      obase[(long)(18 + j) * 512 + f] = ac;
    }
  }
}

__global__ __launch_bounds__(64)
void score_kernel(const float* mq, const float* mc, const float* plan, float* out) {
  int b = blockIdx.x, tid = threadIdx.x;
  __shared__ float pl[400], lq[320], lc[320];
  for (int i = tid; i < 400; i += 64) pl[i] = plan[(long)b * 400 + i];
  for (int i = tid; i < 320; i += 64) { lq[i] = mq[(long)b * 320 + i]; lc[i] = mc[(long)b * 320 + i]; }
  __syncthreads();
  float s = 0.f;
  for (int i = tid; i < 320; i += 64) {
    int q = i / 16, t = i % 16;
    float d = 0.f;
    for (int c = 0; c < 20; ++c) d += pl[q * 20 + c] * lc[c * 16 + t];
    float r = lq[q * 16 + t] - d;
    if (r > 0.f) s += r;
  }
  for (int off = 32; off > 0; off >>= 1) s += __shfl_down(s, off, 64);
  if (tid == 0) out[b] = -s;
}

extern "C" void kernel_launch(void* const* d_in, const int* in_sizes, int n_in,
                              void* d_out, int out_size, void* d_ws, size_t ws_size,
                              hipStream_t stream) {
  (void)in_sizes; (void)n_in; (void)out_size; (void)ws_size;
  const float* node_f = (const float*)d_in[0];
  const float* edge_f = (const float*)d_in[1];
  const float* mult   = (const float*)d_in[2];
  const float* W_ne   = (const float*)d_in[3];
  const float* b_ne   = (const float*)d_in[4];
  const float* W_ee   = (const float*)d_in[5];
  const float* b_ee   = (const float*)d_in[6];
  const float* W_m1   = (const float*)d_in[7];
  const float* b_m1   = (const float*)d_in[8];
  const float* W_m2   = (const float*)d_in[9];
  const float* b_m2   = (const float*)d_in[10];
  const float* W_u1   = (const float*)d_in[11];
  const float* b_u1   = (const float*)d_in[12];
  const float* W_u2   = (const float*)d_in[13];
  const float* b_u2   = (const float*)d_in[14];
  const float* W_c1   = (const float*)d_in[15];
  const float* b_c1   = (const float*)d_in[16];
  const float* W_c2   = (const float*)d_in[17];
  const float* b_c2   = (const float*)d_in[18];
  const float* W_t1   = (const float*)d_in[19];
  const float* b_t1   = (const float*)d_in[20];
  const float* W_t2   = (const float*)d_in[21];
  const float* b_t2   = (const float*)d_in[22];
  const int* from_idx = (const int*)d_in[23];
  const int* to_idx   = (const int*)d_in[24];

  float* ws = (float*)d_ws;
  size_t off = 0;
  auto alloc = [&](size_t n) { float* pp = ws + off; off += n; return pp; };
  float* comb = alloc((size_t)NN * DD);        // 18.9 MB
  float* agg  = alloc((size_t)NN * DD);        // 18.9 MB
  float* y1   = alloc((size_t)NODE_CH * 256);  // 18.9 MB shared hidden buffer
  float* blk  = alloc((size_t)NN * 640);       // 94.4 MB fresh blocks 1..5
  float* mixb = alloc((size_t)NN * 512);       // 75.5 MB mixed blocks 1..4
  float* mq   = alloc((size_t)Bq * NMSS * NTD);
  float* mc   = alloc((size_t)Bq * NMSS * NTD);
  float* plan = alloc((size_t)Bq * NMSS * NMSS);
  // total: 57,688,064 floats = 230.8 MB

  hipMemsetAsync(mixb, 0, (size_t)NN * 512 * sizeof(float), stream);

  for (int t = 0; t < NT; ++t) {
    for (int p_ = 1; p_ <= NP; ++p_) {
      // comb = MLP_c([h | inter]), node rows in 2 chunks
      for (int ch = 0; ch < 2; ++ch) {
        size_t r0 = (size_t)ch * NODE_CH;
        if (p_ == 1) {
          GemmParams g{};
          g.edge_feat = node_f; g.W_ee = W_ne; g.b_ee = b_ne; g.row_base = (int)r0;
          g.W = W_c1; g.bias = b_c1; g.C = y1; g.ldc = 256; g.K = 256; g.Nout = 256;
          gemm_mlp<AK_NFENC, EP_RELU><<<dim3(NODE_CH / 128, 4), 256, 0, stream>>>(g);
        } else {
          GemmParams g{};
          g.A0 = blk  + (size_t)(p_ - 2) * DD + r0 * 640; g.lda0 = 640;
          g.A1 = mixb + (size_t)(p_ - 2) * DD + r0 * 512; g.lda1 = 512;
          g.W = W_c1; g.bias = b_c1; g.C = y1; g.ldc = 256; g.K = 256; g.Nout = 256;
          gemm_mlp<AK_CONCAT2, EP_RELU><<<dim3(NODE_CH / 128, 4), 256, 0, stream>>>(g);
        }
        {
          GemmParams g{};
          g.A0 = y1; g.lda0 = 256; g.W = W_c2; g.bias = b_c2;
          g.C = comb + r0 * DD; g.ldc = DD; g.K = 256; g.Nout = DD;
          gemm_mlp<AK_PLAIN, EP_BIAS><<<dim3(NODE_CH / 128, 2), 256, 0, stream>>>(g);
        }
      }
      hipMemsetAsync(agg, 0, (size_t)NN * DD * sizeof(float), stream);
      // msg MLP over edges, 8 chunks; scatter-add into agg
      for (int ch = 0; ch < 8; ++ch) {
        {
          GemmParams g{};
          g.A0 = comb; g.row_base = ch * EDGE_CH;
          g.from_idx = from_idx; g.to_idx = to_idx;
          g.edge_feat = edge_f; g.W_ee = W_ee; g.b_ee = b_ee;
          g.W = W_m1; g.bias = b_m1; g.C = y1; g.ldc = 256; g.K = 384; g.Nout = 256;
          gemm_mlp<AK_EDGE, EP_RELU><<<dim3(EDGE_CH / 128, 4), 256, 0, stream>>>(g);
        }
        {
          GemmParams g{};
          g.A0 = y1; g.lda0 = 256; g.W = W_m2; g.bias = b_m2;
          g.K = 256; g.Nout = DD;
          g.row_base = ch * EDGE_CH; g.mult = mult; g.to_idx = to_idx; g.agg = agg;
          gemm_mlp<AK_PLAIN, EP_SCATTER><<<dim3(EDGE_CH / 128, 2), 256, 0, stream>>>(g);
        }
      }
      // h = MLP_u([comb | agg]) -> block p_ of blk
      for (int ch = 0; ch < 2; ++ch) {
        size_t r0 = (size_t)ch * NODE_CH;
        {
          GemmParams g{};
          g.A0 = comb + r0 * DD; g.lda0 = DD; g.A1 = agg + r0 * DD; g.lda1 = DD;
          g.W = W_u1; g.bias = b_u1; g.C = y1; g.ldc = 256; g.K = 256; g.Nout = 256;
          gemm_mlp<AK_CONCAT2, EP_RELU><<<dim3(NODE_CH / 128, 4), 256, 0, stream>>>(g);
        }
        {
          GemmParams g{};
          g.A0 = y1; g.lda0 = 256; g.W = W_u2; g.bias = b_u2;
          g.C = blk + (size_t)(p_ - 1) * DD + r0 * 640; g.ldc = 640; g.K = 256; g.Nout = DD;
          gemm_mlp<AK_PLAIN, EP_BIAS><<<dim3(NODE_CH / 128, 2), 256, 0, stream>>>(g);
        }
      }
    }
    mqmc_kernel<<<Bq, 256, 0, stream>>>(blk, W_t1, b_t1, W_t2, b_t2, mq, mc);
    sinkhorn_kernel<<<Bq, 64, 0, stream>>>(mq, mc, plan);
    if (t < NT - 1) mix_kernel<<<Bq, 256, 0, stream>>>(blk, plan, mixb);
  }
  score_kernel<<<Bq, 64, 0, stream>>>(mq, mc, plan, (float*)d_out);
}

// Round 4
// 4532.714 us; speedup vs baseline: 9.8970x; 9.8970x over previous
//
#include <hip/hip_runtime.h>

#define Bq   1024
#define NQS  15
#define NCS  18
#define NMSS 20
#define NPPc 36
#define NN   36864
#define DD   128
#define NTD  16
#define NP   5
#define NT   3
#define NEC  92160   // compact edges (mult!=0): 90 per batch of 135

#define BK_NFENC   0
#define BK_PLAIN2  1
#define BK_COMBAGG 2
#define BK_EDGE    3
#define EP_OUT     0
#define EP_SCATTER 1

typedef __attribute__((ext_vector_type(8))) short short8;
typedef __attribute__((ext_vector_type(4))) short short4v;
typedef __attribute__((ext_vector_type(4))) float float4v;

__device__ __forceinline__ short f2bf(float f) {
  unsigned u = __builtin_bit_cast(unsigned, f);
  u = u + 0x7FFFu + ((u >> 16) & 1u);
  return (short)(u >> 16);
}
__device__ __forceinline__ float bf2f(short s) {
  unsigned u = ((unsigned)(unsigned short)s) << 16;
  return __builtin_bit_cast(float, u);
}

// Swizzled LDS index for H (128 rows x 256 cols bf16 = exactly 64 KB).
// 16B groups (8 shorts) XOR-swizzled by row&7 -> conflict-free b128 reads
// across l16 lanes without padding past 64 KB.
__device__ __forceinline__ int hs_idx(int row, int col) {
  return (row << 8) + ((((col >> 3) ^ (row & 7)) << 3) | (col & 7));
}

struct KP {
  const short* src0; int ld0;     // bf16 B-source, k<128 (comb for EDGE)
  const short* src1; int ld1;     // bf16 B-source, 128<=k<256 (mixb)
  const float* aggf;              // fp32 B-source k>=128 (COMBAGG)
  const float* nf;                // node_features (NFENC)
  const float* W_ne; const float* b_ne;
  const float* ef;                // edge_features (EDGE)
  const float* W_ee; const float* b_ee;
  const int* from_idx; const int* to_idx;
  const short* WT1; int lda1; int ksteps1;   // W1^T [256][K1] bf16
  const float* b1;
  const short* WT2; const float* b2;         // W2^T [128][256] bf16
  short* outb; int ldo;           // bf16 out (EP_OUT)
  float* agg_out;                 // fp32 scatter target (EP_SCATTER)
};

template<int BK>
__device__ __forceinline__ short8 loadB(const KP& p, int node, int fr, int to,
                                        float efv, float nfv, int k0q) {
  short8 r;
  if (BK == BK_PLAIN2) {
    if (k0q < 128) return *(const short8*)(p.src0 + (long)node * p.ld0 + k0q);
    return *(const short8*)(p.src1 + (long)node * p.ld1 + (k0q - 128));
  } else if (BK == BK_COMBAGG) {
    if (k0q < 128) return *(const short8*)(p.src0 + (long)node * 128 + k0q);
    const float* ap = p.aggf + (long)node * 128 + (k0q - 128);
    float4v x0 = *(const float4v*)ap, x1 = *(const float4v*)(ap + 4);
#pragma unroll
    for (int j = 0; j < 4; ++j) { r[j] = f2bf(x0[j]); r[4 + j] = f2bf(x1[j]); }
    return r;
  } else if (BK == BK_NFENC) {
    float4v w0 = *(const float4v*)(p.W_ne + k0q), w1 = *(const float4v*)(p.W_ne + k0q + 4);
    float4v c0 = *(const float4v*)(p.b_ne + k0q), c1 = *(const float4v*)(p.b_ne + k0q + 4);
#pragma unroll
    for (int j = 0; j < 4; ++j) {
      r[j] = f2bf(nfv * w0[j] + c0[j]);
      r[4 + j] = f2bf(nfv * w1[j] + c1[j]);
    }
    return r;
  } else {  // BK_EDGE
    if (k0q < 128) return *(const short8*)(p.src0 + (long)fr * 128 + k0q);
    if (k0q < 256) return *(const short8*)(p.src0 + (long)to * 128 + (k0q - 128));
    int d = k0q - 256;
    float4v w0 = *(const float4v*)(p.W_ee + d), w1 = *(const float4v*)(p.W_ee + d + 4);
    float4v c0 = *(const float4v*)(p.b_ee + d), c1 = *(const float4v*)(p.b_ee + d + 4);
#pragma unroll
    for (int j = 0; j < 4; ++j) {
      r[j] = f2bf(efv * w0[j] + c0[j]);
      r[4 + j] = f2bf(efv * w1[j] + c1[j]);
    }
    return r;
  }
}

// Fused 2-layer MLP over 128 rows/block, computed transposed:
//   H^T[256][128] = relu(W1^T @ A^T + b1);  O^T[128][128] = W2^T @ H^T + b2
// 256 threads = 4 waves in 2(hidden/feat-half) x 2(row-half) grid.
template<int BK, int EPI>
__global__ __launch_bounds__(256, 2) void fused_mlp(KP p) {
  __shared__ short Hs[128 * 256];  // 64 KB, XOR-swizzled (hs_idx)
  const int tid = threadIdx.x, lane = tid & 63, w = tid >> 6;
  const int wm = w >> 1, wn = w & 1, quad = lane >> 4, l16 = lane & 15;
  const int n0 = blockIdx.x * 128;

  int nodes[4]; int fr4[4], to4[4]; float ef4[4], nf4[4];
#pragma unroll
  for (int nt = 0; nt < 4; ++nt) {
    int rrow = n0 + wn * 64 + nt * 16 + l16;
    nodes[nt] = rrow;
    if (BK == BK_EDGE) {
      int b = rrow / 90;
      int e = b * 45 + rrow;         // compact -> global: e = b*135 + (rrow%90)
      nodes[nt] = e;
      fr4[nt] = p.from_idx[e]; to4[nt] = p.to_idx[e]; ef4[nt] = p.ef[e];
    } else if (BK == BK_NFENC) {
      nf4[nt] = p.nf[rrow];
    }
  }

  // ---------- phase 1 ----------
  float4v acc[8][4];
#pragma unroll
  for (int i = 0; i < 8; ++i)
#pragma unroll
    for (int j = 0; j < 4; ++j) acc[i][j] = (float4v)0.f;

  for (int ks = 0; ks < p.ksteps1; ++ks) {
    const int k0q = ks * 32 + quad * 8;
    short8 bfr[4];
#pragma unroll
    for (int nt = 0; nt < 4; ++nt)
      bfr[nt] = loadB<BK>(p, (BK == BK_EDGE) ? 0 : nodes[nt], fr4[nt], to4[nt], ef4[nt], nf4[nt], k0q);
    short8 afr[8];
#pragma unroll
    for (int mt = 0; mt < 8; ++mt)
      afr[mt] = *(const short8*)(p.WT1 + (long)(wm * 128 + mt * 16 + l16) * p.lda1 + k0q);
#pragma unroll
    for (int mt = 0; mt < 8; ++mt)
#pragma unroll
      for (int nt = 0; nt < 4; ++nt)
        acc[mt][nt] = __builtin_amdgcn_mfma_f32_16x16x32_bf16(afr[mt], bfr[nt], acc[mt][nt], 0, 0, 0);
  }
  // epilogue 1: bias+relu, H -> Hs[row][hidden] (swizzled, b64 per tile)
#pragma unroll
  for (int mt = 0; mt < 8; ++mt) {
    const int hrow = wm * 128 + mt * 16 + quad * 4;
    float4v bv = *(const float4v*)(p.b1 + hrow);
#pragma unroll
    for (int nt = 0; nt < 4; ++nt) {
      const int nl = wn * 64 + nt * 16 + l16;
      short4v hv;
#pragma unroll
      for (int r = 0; r < 4; ++r) {
        float v = acc[mt][nt][r] + bv[r];
        hv[r] = f2bf(v > 0.f ? v : 0.f);
      }
      *(short4v*)(&Hs[hs_idx(nl, hrow)]) = hv;
    }
  }
  __syncthreads();

  // ---------- phase 2 ----------
  float4v acc2[4][4];
#pragma unroll
  for (int i = 0; i < 4; ++i)
#pragma unroll
    for (int j = 0; j < 4; ++j) acc2[i][j] = (float4v)0.f;

  for (int ks = 0; ks < 8; ++ks) {
    const int k0q = ks * 32 + quad * 8;
    short8 afr[4], bfr[4];
#pragma unroll
    for (int mt = 0; mt < 4; ++mt)
      afr[mt] = *(const short8*)(p.WT2 + (long)(wm * 64 + mt * 16 + l16) * 256 + k0q);
#pragma unroll
    for (int nt = 0; nt < 4; ++nt)
      bfr[nt] = *(const short8*)(&Hs[hs_idx(wn * 64 + nt * 16 + l16, k0q)]);
#pragma unroll
    for (int mt = 0; mt < 4; ++mt)
#pragma unroll
      for (int nt = 0; nt < 4; ++nt)
        acc2[mt][nt] = __builtin_amdgcn_mfma_f32_16x16x32_bf16(afr[mt], bfr[nt], acc2[mt][nt], 0, 0, 0);
  }
  // epilogue 2
#pragma unroll
  for (int mt = 0; mt < 4; ++mt) {
    const int f = wm * 64 + mt * 16 + quad * 4;
    float4v bv = *(const float4v*)(p.b2 + f);
#pragma unroll
    for (int nt = 0; nt < 4; ++nt) {
      if (EPI == EP_SCATTER) {
        // mult == 1.0 for all compact edges
        float* dst = p.agg_out + (long)to4[nt] * 128 + f;
#pragma unroll
        for (int r = 0; r < 4; ++r) atomicAdd(dst + r, acc2[mt][nt][r] + bv[r]);
      } else {
        short4v ov;
#pragma unroll
        for (int r = 0; r < 4; ++r) ov[r] = f2bf(acc2[mt][nt][r] + bv[r]);
        *(short4v*)(p.outb + (long)nodes[nt] * p.ldo + f) = ov;
      }
    }
  }
}

// W[K][N] fp32 -> WT[N][K] bf16
__global__ __launch_bounds__(256) void wtrans(const float* W, short* WT, int K, int N) {
  int i = blockIdx.x * 256 + threadIdx.x;
  if (i < K * N) {
    int n = i / K, k = i - n * K;
    WT[i] = f2bf(W[(long)k * N + n]);
  }
}

__global__ __launch_bounds__(256)
void mqmc_kernel(const short* blk, const float* W_t1, const float* b_t1,
                 const float* W_t2, const float* b_t2, float* mq, float* mc) {
  int b = blockIdx.x, tid = threadIdx.x;
  __shared__ float xs[33][DD];
  __shared__ float h1[33][NTD];
  for (int i = tid; i < NMSS * NTD; i += 256) {
    int r = i / NTD;
    if (r >= NQS) mq[(long)b * NMSS * NTD + i] = 0.f;
    if (r >= NCS) mc[(long)b * NMSS * NTD + i] = 0.f;
  }
  for (int i = tid; i < 33 * DD; i += 256) {
    int r = i >> 7, d = i & 127;
    int node = (r < NQS) ? b * NPPc + r : b * NPPc + NCS + (r - NQS);
    xs[r][d] = bf2f(blk[(long)node * 640 + 512 + d]);
  }
  __syncthreads();
  for (int i = tid; i < 33 * NTD; i += 256) {
    int r = i / NTD, c = i % NTD;
    float s = b_t1[c];
    for (int k = 0; k < DD; ++k) s += xs[r][k] * W_t1[k * NTD + c];
    h1[r][c] = s > 0.f ? s : 0.f;
  }
  __syncthreads();
  for (int i = tid; i < 33 * NTD; i += 256) {
    int r = i / NTD, c = i % NTD;
    float s = b_t2[c];
    for (int k = 0; k < NTD; ++k) s += h1[r][k] * W_t2[k * NTD + c];
    if (r < NQS) mq[(long)b * NMSS * NTD + r * NTD + c] = s;
    else         mc[(long)b * NMSS * NTD + (r - NQS) * NTD + c] = s;
  }
}

__global__ __launch_bounds__(64)
void sinkhorn_kernel(const float* mq, const float* mc, float* plan) {
  int b = blockIdx.x, tid = threadIdx.x;
  __shared__ float la[NMSS][NMSS];
  __shared__ float lq[NMSS][NTD], lc[NMSS][NTD];
  for (int i = tid; i < NMSS * NTD; i += 64) {
    lq[i / NTD][i % NTD] = mq[(long)b * 320 + i];
    lc[i / NTD][i % NTD] = mc[(long)b * 320 + i];
  }
  __syncthreads();
  for (int i = tid; i < 400; i += 64) {
    int q = i / 20, c = i % 20;
    float s = 0.f;
    for (int t = 0; t < NTD; ++t) s += lq[q][t] * lc[c][t];
    la[q][c] = s * 10.f;
  }
  __syncthreads();
  for (int it = 0; it < 10; ++it) {
    if (tid < 20) {
      float m = -1e30f;
      for (int c = 0; c < 20; ++c) m = fmaxf(m, la[tid][c]);
      float s = 0.f;
      for (int c = 0; c < 20; ++c) s += expf(la[tid][c] - m);
      float l = m + logf(s);
      for (int c = 0; c < 20; ++c) la[tid][c] -= l;
    }
    __syncthreads();
    if (tid < 20) {
      float m = -1e30f;
      for (int q = 0; q < 20; ++q) m = fmaxf(m, la[q][tid]);
      float s = 0.f;
      for (int q = 0; q < 20; ++q) s += expf(la[q][tid] - m);
      float l = m + logf(s);
      for (int q = 0; q < 20; ++q) la[q][tid] -= l;
    }
    __syncthreads();
  }
  for (int i = tid; i < 400; i += 64) plan[(long)b * 400 + i] = expf(la[i / 20][i % 20]);
}

__global__ __launch_bounds__(256)
void mix_kernel(const short* blk, const float* plan, short* mix) {
  int b = blockIdx.x, tid = threadIdx.x;
  __shared__ float pl[400];
  for (int i = tid; i < 400; i += 256) pl[i] = plan[(long)b * 400 + i];
  __syncthreads();
  const short* base = blk + (long)b * NPPc * 640;
  short* obase      = mix + (long)b * NPPc * 512;
  for (int f = tid; f < 512; f += 256) {
    float oq[18], oc[18];
    for (int j = 0; j < 18; ++j) {
      oq[j] = bf2f(base[(long)j * 640 + f]);
      oc[j] = bf2f(base[(long)(18 + j) * 640 + f]);
    }
    for (int j = 0; j < 18; ++j) {
      float aq = 0.f, ac = 0.f;
      for (int k = 0; k < 18; ++k) {
        aq += pl[j * 20 + k] * oc[k];
        ac += pl[k * 20 + j] * oq[k];
      }
      obase[(long)j * 512 + f]        = f2bf(aq);
      obase[(long)(18 + j) * 512 + f] = f2bf(ac);
    }
  }
}

__global__ __launch_bounds__(64)
void score_kernel(const float* mq, const float* mc, const float* plan, float* out) {
  int b = blockIdx.x, tid = threadIdx.x;
  __shared__ float pl[400], lq[320], lc[320];
  for (int i = tid; i < 400; i += 64) pl[i] = plan[(long)b * 400 + i];
  for (int i = tid; i < 320; i += 64) { lq[i] = mq[(long)b * 320 + i]; lc[i] = mc[(long)b * 320 + i]; }
  __syncthreads();
  float s = 0.f;
  for (int i = tid; i < 320; i += 64) {
    int q = i / 16, t = i % 16;
    float d = 0.f;
    for (int c = 0; c < 20; ++c) d += pl[q * 20 + c] * lc[c * 16 + t];
    float r = lq[q * 16 + t] - d;
    if (r > 0.f) s += r;
  }
  for (int off = 32; off > 0; off >>= 1) s += __shfl_down(s, off, 64);
  if (tid == 0) out[b] = -s;
}

extern "C" void kernel_launch(void* const* d_in, const int* in_sizes, int n_in,
                              void* d_out, int out_size, void* d_ws, size_t ws_size,
                              hipStream_t stream) {
  (void)in_sizes; (void)n_in; (void)out_size; (void)ws_size;
  const float* node_f = (const float*)d_in[0];
  const float* edge_f = (const float*)d_in[1];
  const float* W_ne   = (const float*)d_in[3];
  const float* b_ne   = (const float*)d_in[4];
  const float* W_ee   = (const float*)d_in[5];
  const float* b_ee   = (const float*)d_in[6];
  const float* W_m1   = (const float*)d_in[7];
  const float* b_m1   = (const float*)d_in[8];
  const float* W_m2   = (const float*)d_in[9];
  const float* b_m2   = (const float*)d_in[10];
  const float* W_u1   = (const float*)d_in[11];
  const float* b_u1   = (const float*)d_in[12];
  const float* W_u2   = (const float*)d_in[13];
  const float* b_u2   = (const float*)d_in[14];
  const float* W_c1   = (const float*)d_in[15];
  const float* b_c1   = (const float*)d_in[16];
  const float* W_c2   = (const float*)d_in[17];
  const float* b_c2   = (const float*)d_in[18];
  const float* W_t1   = (const float*)d_in[19];
  const float* b_t1   = (const float*)d_in[20];
  const float* W_t2   = (const float*)d_in[21];
  const float* b_t2   = (const float*)d_in[22];
  const int* from_idx = (const int*)d_in[23];
  const int* to_idx   = (const int*)d_in[24];

  float* ws = (float*)d_ws;
  size_t off = 0;
  auto alloc = [&](size_t nfloats) { float* pp = ws + off; off += nfloats; return pp; };
  short* comb = (short*)alloc((size_t)NN * 64);    // bf16 [NN][128]
  float* agg  = alloc((size_t)NN * 128);           // fp32 [NN][128]
  short* blk  = (short*)alloc((size_t)NN * 320);   // bf16 [NN][640] fresh blocks 1..5
  short* mixb = (short*)alloc((size_t)NN * 256);   // bf16 [NN][512] mixed blocks 1..4
  short* WTc1 = (short*)alloc(32768);              // [256][256]
  short* WTm1 = (short*)alloc(49152);              // [256][384]
  short* WTu1 = (short*)alloc(32768);
  short* WTc2 = (short*)alloc(16384);              // [128][256]
  short* WTm2 = (short*)alloc(16384);
  short* WTu2 = (short*)alloc(16384);
  float* mq   = alloc((size_t)Bq * 320);
  float* mc   = alloc((size_t)Bq * 320);
  float* plan = alloc((size_t)Bq * 400);

  wtrans<<<(256 * 256 + 255) / 256, 256, 0, stream>>>(W_c1, WTc1, 256, 256);
  wtrans<<<(384 * 256 + 255) / 256, 256, 0, stream>>>(W_m1, WTm1, 384, 256);
  wtrans<<<(256 * 256 + 255) / 256, 256, 0, stream>>>(W_u1, WTu1, 256, 256);
  wtrans<<<(256 * 128 + 255) / 256, 256, 0, stream>>>(W_c2, WTc2, 256, 128);
  wtrans<<<(256 * 128 + 255) / 256, 256, 0, stream>>>(W_m2, WTm2, 256, 128);
  wtrans<<<(256 * 128 + 255) / 256, 256, 0, stream>>>(W_u2, WTu2, 256, 128);
  hipMemsetAsync(mixb, 0, (size_t)NN * 512 * sizeof(short), stream);

  for (int t = 0; t < NT; ++t) {
    // p=1 is t-invariant (h=nf_enc, inter=0): compute only at t=0; blk block1 persists.
    int pstart = (t == 0) ? 1 : 2;
    for (int p_ = pstart; p_ <= NP; ++p_) {
      // ---- comb MLP ----
      {
        KP g{};
        g.b1 = b_c1; g.WT2 = WTc2; g.b2 = b_c2;
        g.outb = comb; g.ldo = 128;
        if (p_ == 1) {
          g.nf = node_f; g.W_ne = W_ne; g.b_ne = b_ne;
          g.WT1 = WTc1; g.lda1 = 256; g.ksteps1 = 4;  // inter==0 -> K_eff=128
          fused_mlp<BK_NFENC, EP_OUT><<<NN / 128, 256, 0, stream>>>(g);
        } else {
          g.src0 = blk  + (size_t)(p_ - 2) * 128; g.ld0 = 640;
          g.src1 = mixb + (size_t)(p_ - 2) * 128; g.ld1 = 512;
          g.WT1 = WTc1; g.lda1 = 256; g.ksteps1 = 8;
          fused_mlp<BK_PLAIN2, EP_OUT><<<NN / 128, 256, 0, stream>>>(g);
        }
      }
      hipMemsetAsync(agg, 0, (size_t)NN * 128 * sizeof(float), stream);
      // ---- msg MLP over compact edges + scatter ----
      {
        KP g{};
        g.src0 = comb;
        g.ef = edge_f; g.W_ee = W_ee; g.b_ee = b_ee;
        g.from_idx = from_idx; g.to_idx = to_idx;
        g.WT1 = WTm1; g.lda1 = 384; g.ksteps1 = 12;
        g.b1 = b_m1; g.WT2 = WTm2; g.b2 = b_m2;
        g.agg_out = agg;
        fused_mlp<BK_EDGE, EP_SCATTER><<<NEC / 128, 256, 0, stream>>>(g);
      }
      // ---- upd MLP -> blk block p_ ----
      {
        KP g{};
        g.src0 = comb; g.aggf = agg;
        g.WT1 = WTu1; g.lda1 = 256; g.ksteps1 = 8;
        g.b1 = b_u1; g.WT2 = WTu2; g.b2 = b_u2;
        g.outb = blk + (size_t)(p_ - 1) * 128; g.ldo = 640;
        fused_mlp<BK_COMBAGG, EP_OUT><<<NN / 128, 256, 0, stream>>>(g);
      }
    }
    mqmc_kernel<<<Bq, 256, 0, stream>>>(blk, W_t1, b_t1, W_t2, b_t2, mq, mc);
    sinkhorn_kernel<<<Bq, 64, 0, stream>>>(mq, mc, plan);
    if (t < NT - 1) mix_kernel<<<Bq, 256, 0, stream>>>(blk, plan, mixb);
  }
  score_kernel<<<Bq, 64, 0, stream>>>(mq, mc, plan, (float*)d_out);
}